// Round 1
// baseline (259.963 us; speedup 1.0000x reference)
//
#include <hip/hip_runtime.h>
#include <stdint.h>

#define H_ 96
#define W_ 96
#define C_ 256
#define O_ 256
#define N_ 2
#define HW_ (H_*W_)          // 9216
#define M_ (N_*HW_)          // 18432
#define GK 2304              // C_*9

typedef __bf16 bf16x8 __attribute__((ext_vector_type(8)));
typedef float f32x4 __attribute__((ext_vector_type(4)));

__device__ __forceinline__ unsigned short f2bf(float f) {
  union { float f; unsigned int u; } v; v.f = f;
  unsigned int u = v.u;
  return (unsigned short)((u + 0x7fffu + ((u >> 16) & 1u)) >> 16);
}

// ---------------- Kernel 1: NCHW -> NHWC transpose (per n: 256 x 9216 -> 9216 x 256)
__global__ __launch_bounds__(256) void k_transpose(const float* __restrict__ x,
                                                   float* __restrict__ xt) {
  __shared__ float tile[32][33];
  const int n = blockIdx.z;
  const int c0 = blockIdx.y * 32;
  const int p0 = blockIdx.x * 32;  // hw
  const int tx = threadIdx.x;      // 0..31
  const int ty = threadIdx.y;      // 0..7
  const float* xp = x + (size_t)n * C_ * HW_;
  float* xtp = xt + (size_t)n * C_ * HW_;
#pragma unroll
  for (int i = 0; i < 32; i += 8)
    tile[ty + i][tx] = xp[(size_t)(c0 + ty + i) * HW_ + p0 + tx];
  __syncthreads();
#pragma unroll
  for (int i = 0; i < 32; i += 8)
    xtp[(size_t)(p0 + ty + i) * C_ + c0 + tx] = tile[tx][ty + i];
}

// ---------------- Kernel 2: w_deform (O,C,3,3) -> bf16 Wp[o][k*256+c]
__global__ __launch_bounds__(256) void k_wt(const float* __restrict__ w,
                                            unsigned short* __restrict__ wp) {
  int idx = blockIdx.x * 256 + threadIdx.x;
  if (idx >= O_ * GK) return;
  int o = idx / GK;
  int kk = idx - o * GK;
  int k = kk >> 8;
  int c = kk & 255;
  wp[idx] = f2bf(w[(size_t)(o * C_ + c) * 9 + k]);
}

// ---------------- Kernel 3: offset convs (tm:4, tr:2) -> absolute sample coords
// coords[m*18 + k*2 + {0,1}] = (py, px)
__global__ __launch_bounds__(256) void k_offsets(const float* __restrict__ xt,
                                                 const float* __restrict__ w_tm,
                                                 const float* __restrict__ b_tm,
                                                 const float* __restrict__ w_tr,
                                                 const float* __restrict__ b_tr,
                                                 float* __restrict__ coords) {
  __shared__ float lw[9 * 6 * 256];  // [k][j][c], 55296 B
  const int tid = threadIdx.x;
  for (int idx = tid; idx < 9 * 6 * 256; idx += 256) {
    int k = idx / 1536;
    int rem = idx - k * 1536;
    int j = rem >> 8;
    int c = rem & 255;
    float v = (j < 4) ? w_tm[(size_t)(j * C_ + c) * 9 + k]
                      : w_tr[(size_t)((j - 4) * C_ + c) * 9 + k];
    lw[idx] = v;
  }
  __syncthreads();
  const int wave = tid >> 6, lane = tid & 63;
  for (int i = 0; i < 8; i++) {
    const int m = blockIdx.x * 32 + wave * 8 + i;
    const int n = m / HW_;
    const int hw = m - n * HW_;
    const int h = hw / W_;
    const int w = hw - h * W_;
    float a0 = 0.f, a1 = 0.f, a2 = 0.f, a3 = 0.f, a4 = 0.f, a5 = 0.f;
    for (int ky = 0; ky < 3; ky++) {
      int y = h + ky - 1;
      if (y < 0 || y >= H_) continue;
      for (int kx = 0; kx < 3; kx++) {
        int xx = w + kx - 1;
        if (xx < 0 || xx >= W_) continue;
        const float* rowp = xt + (size_t)((n * H_ + y) * W_ + xx) * C_;
        const float* wk = lw + (ky * 3 + kx) * 1536;
#pragma unroll
        for (int ci = 0; ci < 4; ci++) {
          int c = lane + (ci << 6);
          float xv = rowp[c];
          a0 += xv * wk[c];
          a1 += xv * wk[256 + c];
          a2 += xv * wk[512 + c];
          a3 += xv * wk[768 + c];
          a4 += xv * wk[1024 + c];
          a5 += xv * wk[1280 + c];
        }
      }
    }
#pragma unroll
    for (int s = 32; s > 0; s >>= 1) {
      a0 += __shfl_xor(a0, s, 64);
      a1 += __shfl_xor(a1, s, 64);
      a2 += __shfl_xor(a2, s, 64);
      a3 += __shfl_xor(a3, s, 64);
      a4 += __shfl_xor(a4, s, 64);
      a5 += __shfl_xor(a5, s, 64);
    }
    if (lane < 9) {
      float tm0 = a0 + b_tm[0];
      float tm1 = a1 + b_tm[1];
      float tm2 = a2 + b_tm[2];
      float tm3 = a3 + b_tm[3];
      float tr0 = a4 + b_tr[0];
      float tr1 = a5 + b_tr[1];
      float ry = (float)(lane / 3) - 1.f;
      float rx = (float)(lane % 3) - 1.f;
      float py = (float)h + tr0 + tm0 * ry + tm1 * rx;
      float px = (float)w + tr1 + tm2 * ry + tm3 * rx;
      coords[(size_t)m * 18 + lane * 2 + 0] = py;
      coords[(size_t)m * 18 + lane * 2 + 1] = px;
    }
  }
}

// ---------------- Kernel 4: bilinear sampling -> bf16 A[m][k*256+c]
__global__ __launch_bounds__(256) void k_sample(const float* __restrict__ xt,
                                                const float* __restrict__ coords,
                                                unsigned short* __restrict__ A) {
  const int wave = threadIdx.x >> 6, lane = threadIdx.x & 63;
  const int p = blockIdx.x * 4 + wave;  // (m,k) pair, < 165888
  const int m = p / 9;
  const int k = p - m * 9;
  const int n = m / HW_;
  const float py = coords[(size_t)m * 18 + k * 2 + 0];
  const float px = coords[(size_t)m * 18 + k * 2 + 1];
  const float fy = floorf(py), fx = floorf(px);
  const float wy = py - fy, wx = px - fx;
  const int y0 = (int)fy, x0 = (int)fx;
  const int y1 = y0 + 1, x1 = x0 + 1;
  const float vy0 = (y0 >= 0 && y0 < H_) ? 1.f : 0.f;
  const float vy1 = (y1 >= 0 && y1 < H_) ? 1.f : 0.f;
  const float vx0 = (x0 >= 0 && x0 < W_) ? 1.f : 0.f;
  const float vx1 = (x1 >= 0 && x1 < W_) ? 1.f : 0.f;
  const float w00 = (1.f - wy) * (1.f - wx) * vy0 * vx0;
  const float w01 = (1.f - wy) * wx * vy0 * vx1;
  const float w10 = wy * (1.f - wx) * vy1 * vx0;
  const float w11 = wy * wx * vy1 * vx1;
  const int cy0 = min(max(y0, 0), H_ - 1), cy1 = min(max(y1, 0), H_ - 1);
  const int cx0 = min(max(x0, 0), W_ - 1), cx1 = min(max(x1, 0), W_ - 1);
  const float* r00 = xt + (size_t)((n * H_ + cy0) * W_ + cx0) * C_;
  const float* r01 = xt + (size_t)((n * H_ + cy0) * W_ + cx1) * C_;
  const float* r10 = xt + (size_t)((n * H_ + cy1) * W_ + cx0) * C_;
  const float* r11 = xt + (size_t)((n * H_ + cy1) * W_ + cx1) * C_;
  unsigned short* dst = A + (size_t)m * GK + k * C_;
#pragma unroll
  for (int i = 0; i < 4; i++) {
    int c = lane + (i << 6);
    float v = w00 * r00[c] + w01 * r01[c] + w10 * r10[c] + w11 * r11[c];
    dst[c] = f2bf(v);
  }
}

// ---------------- Kernel 5: GEMM out[m][o] = sum_kk A[m][kk]*Wp[o][kk], fused BN+res+ReLU
// m97 pattern: 128x128 block tile, BK=64, global_load_lds(16B), 16x16x32 bf16 MFMA.
__global__ __launch_bounds__(256, 2) void k_gemm(const unsigned short* __restrict__ A,
                                                 const unsigned short* __restrict__ Wp,
                                                 const float* __restrict__ xres,
                                                 const float* __restrict__ gamma,
                                                 const float* __restrict__ beta,
                                                 const float* __restrict__ mean,
                                                 const float* __restrict__ var,
                                                 float* __restrict__ out) {
  __shared__ unsigned short As[128 * 64] __attribute__((aligned(16)));
  __shared__ unsigned short Bs[128 * 64] __attribute__((aligned(16)));
  const int tid = threadIdx.x;
  const int wave = tid >> 6, lane = tid & 63;
  const int wm = wave & 1, wo = wave >> 1;
  const int bm = blockIdx.x >> 1, bo = blockIdx.x & 1;
  const int m0 = bm * 128, o0 = bo * 128;
  const int row = lane & 15, quad = lane >> 4;

  f32x4 acc[4][4] = {};

  for (int k0 = 0; k0 < GK; k0 += 64) {
#pragma unroll
    for (int i = 0; i < 4; i++) {
      int g = i * 256 + tid;
      int r = g >> 3, c8 = g & 7;
      __builtin_amdgcn_global_load_lds(
          (const __attribute__((address_space(1))) void*)(A + (size_t)(m0 + r) * GK + k0 + c8 * 8),
          (__attribute__((address_space(3))) void*)(&As[(i * 256 + wave * 64) * 8]),
          16, 0, 0);
      __builtin_amdgcn_global_load_lds(
          (const __attribute__((address_space(1))) void*)(Wp + (size_t)(o0 + r) * GK + k0 + c8 * 8),
          (__attribute__((address_space(3))) void*)(&Bs[(i * 256 + wave * 64) * 8]),
          16, 0, 0);
    }
    __syncthreads();
#pragma unroll
    for (int ks = 0; ks < 64; ks += 32) {
      bf16x8 av[4], bv[4];
#pragma unroll
      for (int t = 0; t < 4; t++) {
        av[t] = *(const bf16x8*)(const void*)&As[(wm * 64 + t * 16 + row) * 64 + ks + quad * 8];
        bv[t] = *(const bf16x8*)(const void*)&Bs[(wo * 64 + t * 16 + row) * 64 + ks + quad * 8];
      }
#pragma unroll
      for (int mt = 0; mt < 4; mt++)
#pragma unroll
        for (int ot = 0; ot < 4; ot++)
          acc[mt][ot] = __builtin_amdgcn_mfma_f32_16x16x32_bf16(av[mt], bv[ot], acc[mt][ot], 0, 0, 0);
    }
    __syncthreads();
  }

  const int n = m0 / HW_;  // tiles never cross n (9216 = 72*128)
#pragma unroll
  for (int ot = 0; ot < 4; ot++) {
    int o = o0 + wo * 64 + ot * 16 + row;
    float sc = rsqrtf(var[o] + 1e-5f) * gamma[o];
    float bi = beta[o] - mean[o] * sc;
    const size_t obase = (size_t)(n * O_ + o) * HW_;
#pragma unroll
    for (int mt = 0; mt < 4; mt++) {
      int mrow = m0 + wm * 64 + mt * 16 + quad * 4 - n * HW_;
#pragma unroll
      for (int r = 0; r < 4; r++) {
        int hw = mrow + r;
        float v = acc[mt][ot][r] * sc + bi + xres[obase + hw];
        out[obase + hw] = fmaxf(v, 0.f);
      }
    }
  }
}

extern "C" void kernel_launch(void* const* d_in, const int* in_sizes, int n_in,
                              void* d_out, int out_size, void* d_ws, size_t ws_size,
                              hipStream_t stream) {
  const float* x     = (const float*)d_in[0];
  // d_in[1] mask_attention: unused by reference
  const float* w_tm  = (const float*)d_in[2];
  const float* b_tm  = (const float*)d_in[3];
  const float* w_tr  = (const float*)d_in[4];
  const float* b_tr  = (const float*)d_in[5];
  const float* w_df  = (const float*)d_in[6];
  const float* gamma = (const float*)d_in[7];
  const float* beta  = (const float*)d_in[8];
  const float* mean  = (const float*)d_in[9];
  const float* var   = (const float*)d_in[10];
  float* out = (float*)d_out;

  char* ws = (char*)d_ws;
  float* xt              = (float*)(ws);                                   // 18,874,368 B
  float* coords          = (float*)(ws + 18874368);                        //  1,327,104 B
  unsigned short* WpB    = (unsigned short*)(ws + 18874368 + 1327104);     //  1,179,648 B
  unsigned short* Amat   = (unsigned short*)(ws + 18874368 + 1327104 + 1179648); // 84,934,656 B

  k_transpose<<<dim3(HW_ / 32, C_ / 32, N_), dim3(32, 8), 0, stream>>>(x, xt);
  k_wt<<<(O_ * GK) / 256, 256, 0, stream>>>(w_df, WpB);
  k_offsets<<<M_ / 32, 256, 0, stream>>>(xt, w_tm, b_tm, w_tr, b_tr, coords);
  k_sample<<<(M_ * 9) / 4, 256, 0, stream>>>(xt, coords, Amat);
  k_gemm<<<(M_ / 128) * 2, 256, 0, stream>>>(Amat, WpB, x, gamma, beta, mean, var, out);
}

// Round 2
// 254.796 us; speedup vs baseline: 1.0203x; 1.0203x over previous
//
#include <hip/hip_runtime.h>
#include <stdint.h>

#define H_ 96
#define W_ 96
#define C_ 256
#define O_ 256
#define N_ 2
#define HW_ (H_*W_)          // 9216
#define M_ (N_*HW_)          // 18432
#define GK 2304              // C_*9

typedef __bf16 bf16x8 __attribute__((ext_vector_type(8)));
typedef float f32x4 __attribute__((ext_vector_type(4)));

__device__ __forceinline__ unsigned short f2bf(float f) {
  union { float f; unsigned int u; } v; v.f = f;
  unsigned int u = v.u;
  return (unsigned short)((u + 0x7fffu + ((u >> 16) & 1u)) >> 16);
}

// ---------------- Kernel 1: NCHW -> NHWC transpose (per n: 256 x 9216 -> 9216 x 256)
__global__ __launch_bounds__(256) void k_transpose(const float* __restrict__ x,
                                                   float* __restrict__ xt) {
  __shared__ float tile[32][33];
  const int n = blockIdx.z;
  const int c0 = blockIdx.y * 32;
  const int p0 = blockIdx.x * 32;  // hw
  const int tx = threadIdx.x;      // 0..31
  const int ty = threadIdx.y;      // 0..7
  const float* xp = x + (size_t)n * C_ * HW_;
  float* xtp = xt + (size_t)n * C_ * HW_;
#pragma unroll
  for (int i = 0; i < 32; i += 8)
    tile[ty + i][tx] = xp[(size_t)(c0 + ty + i) * HW_ + p0 + tx];
  __syncthreads();
#pragma unroll
  for (int i = 0; i < 32; i += 8)
    xtp[(size_t)(p0 + ty + i) * C_ + c0 + tx] = tile[tx][ty + i];
}

// ---------------- Kernel 2: w_deform (O,C,3,3) -> bf16 Wp[o][k*256+c]
__global__ __launch_bounds__(256) void k_wt(const float* __restrict__ w,
                                            unsigned short* __restrict__ wp) {
  int idx = blockIdx.x * 256 + threadIdx.x;
  if (idx >= O_ * GK) return;
  int o = idx / GK;
  int kk = idx - o * GK;
  int k = kk >> 8;
  int c = kk & 255;
  wp[idx] = f2bf(w[(size_t)(o * C_ + c) * 9 + k]);
}

// ---------------- Kernel 3: offset convs (tm:4, tr:2) -> absolute sample coords
// Thread = (m, channel-quarter q). Wave = 16 m x 4 q. NCHW x loads (coalesced
// over m). Weights in LDS [tap][q][cc][j] with +2-word pad per (tap,q) section
// so the 4 q-lanes land on distinct banks; 6 j-weights contiguous & 8B-aligned.
// coords[m*18 + t*2 + {0,1}] = (py, px)
#define WSEC 386  // 64*6 + 2 pad words
__global__ __launch_bounds__(256) void k_offsets(const float* __restrict__ x,
                                                 const float* __restrict__ w_tm,
                                                 const float* __restrict__ b_tm,
                                                 const float* __restrict__ w_tr,
                                                 const float* __restrict__ b_tr,
                                                 float* __restrict__ coords) {
  __shared__ float lw[36 * WSEC];  // 55,584 B
  const int tid = threadIdx.x;
  for (int idx = tid; idx < 9 * 256 * 6; idx += 256) {
    int k = idx / 1536;
    int rem = idx - k * 1536;
    int c = rem / 6;
    int j = rem - c * 6;
    float v = (j < 4) ? w_tm[(size_t)(j * C_ + c) * 9 + k]
                      : w_tr[(size_t)((j - 4) * C_ + c) * 9 + k];
    lw[(k * 4 + (c >> 6)) * WSEC + (c & 63) * 6 + j] = v;
  }
  __syncthreads();

  const int wave = tid >> 6, lane = tid & 63;
  const int mm = lane & 15, q = lane >> 4;
  const int m = blockIdx.x * 64 + wave * 16 + mm;
  const int n = m / HW_;
  const int hw = m - n * HW_;
  const int h = hw / W_;
  const int w = hw - h * W_;
  const float* xb = x + (size_t)n * C_ * HW_ + (size_t)(q * 64) * HW_ + hw;

  float a0 = 0.f, a1 = 0.f, a2 = 0.f, a3 = 0.f, a4 = 0.f, a5 = 0.f;
#pragma unroll
  for (int ky = 0; ky < 3; ky++) {
    const int y = h + ky - 1;
    const bool vy = (y >= 0) && (y < H_);
#pragma unroll
    for (int kx = 0; kx < 3; kx++) {
      const int xx = w + kx - 1;
      const bool valid = vy && (xx >= 0) && (xx < W_);
      const float* xp = xb + (ky - 1) * W_ + (kx - 1);
      const float* wk = lw + ((ky * 3 + kx) * 4 + q) * WSEC;
#pragma unroll 8
      for (int cc = 0; cc < 64; cc++) {
        float xv = valid ? xp[(size_t)cc * HW_] : 0.f;
        const float* wr = wk + cc * 6;
        a0 += xv * wr[0];
        a1 += xv * wr[1];
        a2 += xv * wr[2];
        a3 += xv * wr[3];
        a4 += xv * wr[4];
        a5 += xv * wr[5];
      }
    }
  }
  // reduce across q (lane bits 4,5)
  a0 += __shfl_xor(a0, 16, 64); a0 += __shfl_xor(a0, 32, 64);
  a1 += __shfl_xor(a1, 16, 64); a1 += __shfl_xor(a1, 32, 64);
  a2 += __shfl_xor(a2, 16, 64); a2 += __shfl_xor(a2, 32, 64);
  a3 += __shfl_xor(a3, 16, 64); a3 += __shfl_xor(a3, 32, 64);
  a4 += __shfl_xor(a4, 16, 64); a4 += __shfl_xor(a4, 32, 64);
  a5 += __shfl_xor(a5, 16, 64); a5 += __shfl_xor(a5, 32, 64);

  if (q == 0) {
    const float tm0 = a0 + b_tm[0];
    const float tm1 = a1 + b_tm[1];
    const float tm2 = a2 + b_tm[2];
    const float tm3 = a3 + b_tm[3];
    const float tr0 = a4 + b_tr[0];
    const float tr1 = a5 + b_tr[1];
#pragma unroll
    for (int t = 0; t < 9; t++) {
      const float ry = (float)(t / 3) - 1.f;
      const float rx = (float)(t % 3) - 1.f;
      coords[(size_t)m * 18 + t * 2 + 0] = (float)h + tr0 + tm0 * ry + tm1 * rx;
      coords[(size_t)m * 18 + t * 2 + 1] = (float)w + tr1 + tm2 * ry + tm3 * rx;
    }
  }
}

// ---------------- Kernel 4: bilinear sampling -> bf16 A[m][k*256+c]
__global__ __launch_bounds__(256) void k_sample(const float* __restrict__ xt,
                                                const float* __restrict__ coords,
                                                unsigned short* __restrict__ A) {
  const int wave = threadIdx.x >> 6, lane = threadIdx.x & 63;
  const int p = blockIdx.x * 4 + wave;  // (m,k) pair, < 165888
  const int m = p / 9;
  const int k = p - m * 9;
  const int n = m / HW_;
  const float py = coords[(size_t)m * 18 + k * 2 + 0];
  const float px = coords[(size_t)m * 18 + k * 2 + 1];
  const float fy = floorf(py), fx = floorf(px);
  const float wy = py - fy, wx = px - fx;
  const int y0 = (int)fy, x0 = (int)fx;
  const int y1 = y0 + 1, x1 = x0 + 1;
  const float vy0 = (y0 >= 0 && y0 < H_) ? 1.f : 0.f;
  const float vy1 = (y1 >= 0 && y1 < H_) ? 1.f : 0.f;
  const float vx0 = (x0 >= 0 && x0 < W_) ? 1.f : 0.f;
  const float vx1 = (x1 >= 0 && x1 < W_) ? 1.f : 0.f;
  const float w00 = (1.f - wy) * (1.f - wx) * vy0 * vx0;
  const float w01 = (1.f - wy) * wx * vy0 * vx1;
  const float w10 = wy * (1.f - wx) * vy1 * vx0;
  const float w11 = wy * wx * vy1 * vx1;
  const int cy0 = min(max(y0, 0), H_ - 1), cy1 = min(max(y1, 0), H_ - 1);
  const int cx0 = min(max(x0, 0), W_ - 1), cx1 = min(max(x1, 0), W_ - 1);
  const float* r00 = xt + (size_t)((n * H_ + cy0) * W_ + cx0) * C_;
  const float* r01 = xt + (size_t)((n * H_ + cy0) * W_ + cx1) * C_;
  const float* r10 = xt + (size_t)((n * H_ + cy1) * W_ + cx0) * C_;
  const float* r11 = xt + (size_t)((n * H_ + cy1) * W_ + cx1) * C_;
  unsigned short* dst = A + (size_t)m * GK + k * C_;
#pragma unroll
  for (int i = 0; i < 4; i++) {
    int c = lane + (i << 6);
    float v = w00 * r00[c] + w01 * r01[c] + w10 * r10[c] + w11 * r11[c];
    dst[c] = f2bf(v);
  }
}

// ---------------- Kernel 5: GEMM out[m][o] = sum_kk A[m][kk]*Wp[o][kk], fused BN+res+ReLU
// m97 pattern: 128x128 block tile, BK=64, global_load_lds(16B), 16x16x32 bf16 MFMA.
__global__ __launch_bounds__(256, 2) void k_gemm(const unsigned short* __restrict__ A,
                                                 const unsigned short* __restrict__ Wp,
                                                 const float* __restrict__ xres,
                                                 const float* __restrict__ gamma,
                                                 const float* __restrict__ beta,
                                                 const float* __restrict__ mean,
                                                 const float* __restrict__ var,
                                                 float* __restrict__ out) {
  __shared__ unsigned short As[128 * 64] __attribute__((aligned(16)));
  __shared__ unsigned short Bs[128 * 64] __attribute__((aligned(16)));
  const int tid = threadIdx.x;
  const int wave = tid >> 6, lane = tid & 63;
  const int wm = wave & 1, wo = wave >> 1;
  const int bm = blockIdx.x >> 1, bo = blockIdx.x & 1;
  const int m0 = bm * 128, o0 = bo * 128;
  const int row = lane & 15, quad = lane >> 4;

  f32x4 acc[4][4] = {};

  for (int k0 = 0; k0 < GK; k0 += 64) {
#pragma unroll
    for (int i = 0; i < 4; i++) {
      int g = i * 256 + tid;
      int r = g >> 3, c8 = g & 7;
      __builtin_amdgcn_global_load_lds(
          (const __attribute__((address_space(1))) void*)(A + (size_t)(m0 + r) * GK + k0 + c8 * 8),
          (__attribute__((address_space(3))) void*)(&As[(i * 256 + wave * 64) * 8]),
          16, 0, 0);
      __builtin_amdgcn_global_load_lds(
          (const __attribute__((address_space(1))) void*)(Wp + (size_t)(o0 + r) * GK + k0 + c8 * 8),
          (__attribute__((address_space(3))) void*)(&Bs[(i * 256 + wave * 64) * 8]),
          16, 0, 0);
    }
    __syncthreads();
#pragma unroll
    for (int ks = 0; ks < 64; ks += 32) {
      bf16x8 av[4], bv[4];
#pragma unroll
      for (int t = 0; t < 4; t++) {
        av[t] = *(const bf16x8*)(const void*)&As[(wm * 64 + t * 16 + row) * 64 + ks + quad * 8];
        bv[t] = *(const bf16x8*)(const void*)&Bs[(wo * 64 + t * 16 + row) * 64 + ks + quad * 8];
      }
#pragma unroll
      for (int mt = 0; mt < 4; mt++)
#pragma unroll
        for (int ot = 0; ot < 4; ot++)
          acc[mt][ot] = __builtin_amdgcn_mfma_f32_16x16x32_bf16(av[mt], bv[ot], acc[mt][ot], 0, 0, 0);
    }
    __syncthreads();
  }

  const int n = m0 / HW_;  // tiles never cross n (9216 = 72*128)
#pragma unroll
  for (int ot = 0; ot < 4; ot++) {
    int o = o0 + wo * 64 + ot * 16 + row;
    float sc = rsqrtf(var[o] + 1e-5f) * gamma[o];
    float bi = beta[o] - mean[o] * sc;
    const size_t obase = (size_t)(n * O_ + o) * HW_;
#pragma unroll
    for (int mt = 0; mt < 4; mt++) {
      int mrow = m0 + wm * 64 + mt * 16 + quad * 4 - n * HW_;
#pragma unroll
      for (int r = 0; r < 4; r++) {
        int hw = mrow + r;
        float v = acc[mt][ot][r] * sc + bi + xres[obase + hw];
        out[obase + hw] = fmaxf(v, 0.f);
      }
    }
  }
}

extern "C" void kernel_launch(void* const* d_in, const int* in_sizes, int n_in,
                              void* d_out, int out_size, void* d_ws, size_t ws_size,
                              hipStream_t stream) {
  const float* x     = (const float*)d_in[0];
  // d_in[1] mask_attention: unused by reference
  const float* w_tm  = (const float*)d_in[2];
  const float* b_tm  = (const float*)d_in[3];
  const float* w_tr  = (const float*)d_in[4];
  const float* b_tr  = (const float*)d_in[5];
  const float* w_df  = (const float*)d_in[6];
  const float* gamma = (const float*)d_in[7];
  const float* beta  = (const float*)d_in[8];
  const float* mean  = (const float*)d_in[9];
  const float* var   = (const float*)d_in[10];
  float* out = (float*)d_out;

  char* ws = (char*)d_ws;
  float* xt              = (float*)(ws);                                   // 18,874,368 B
  float* coords          = (float*)(ws + 18874368);                        //  1,327,104 B
  unsigned short* WpB    = (unsigned short*)(ws + 18874368 + 1327104);     //  1,179,648 B
  unsigned short* Amat   = (unsigned short*)(ws + 18874368 + 1327104 + 1179648); // 84,934,656 B

  k_transpose<<<dim3(HW_ / 32, C_ / 32, N_), dim3(32, 8), 0, stream>>>(x, xt);
  k_wt<<<(O_ * GK) / 256, 256, 0, stream>>>(w_df, WpB);
  k_offsets<<<M_ / 64, 256, 0, stream>>>(x, w_tm, b_tm, w_tr, b_tr, coords);
  k_sample<<<(M_ * 9) / 4, 256, 0, stream>>>(xt, coords, Amat);
  k_gemm<<<(M_ / 128) * 2, 256, 0, stream>>>(Amat, WpB, x, gamma, beta, mean, var, out);
}

// Round 3
// 236.053 us; speedup vs baseline: 1.1013x; 1.0794x over previous
//
#include <hip/hip_runtime.h>
#include <stdint.h>

#define H_ 96
#define W_ 96
#define C_ 256
#define O_ 256
#define N_ 2
#define HW_ (H_*W_)          // 9216
#define M_ (N_*HW_)          // 18432
#define GK 2304              // C_*9

typedef __bf16 bf16x8 __attribute__((ext_vector_type(8)));
typedef float f32x4 __attribute__((ext_vector_type(4)));
typedef unsigned short us4 __attribute__((ext_vector_type(4)));

__device__ __forceinline__ unsigned short f2bf(float f) {
  union { float f; unsigned int u; } v; v.f = f;
  unsigned int u = v.u;
  return (unsigned short)((u + 0x7fffu + ((u >> 16) & 1u)) >> 16);
}
__device__ __forceinline__ float bf2f(unsigned short h) {
  union { unsigned int u; float f; } v; v.u = ((unsigned int)h) << 16;
  return v.f;
}

// ---------------- Kernel 1: NCHW fp32 -> NHWC bf16 transpose
__global__ __launch_bounds__(256) void k_transpose(const float* __restrict__ x,
                                                   unsigned short* __restrict__ xt) {
  __shared__ float tile[32][33];
  const int n = blockIdx.z;
  const int c0 = blockIdx.y * 32;
  const int p0 = blockIdx.x * 32;  // hw
  const int tx = threadIdx.x;      // 0..31
  const int ty = threadIdx.y;      // 0..7
  const float* xp = x + (size_t)n * C_ * HW_;
  unsigned short* xtp = xt + (size_t)n * C_ * HW_;
#pragma unroll
  for (int i = 0; i < 32; i += 8)
    tile[ty + i][tx] = xp[(size_t)(c0 + ty + i) * HW_ + p0 + tx];
  __syncthreads();
#pragma unroll
  for (int i = 0; i < 32; i += 8)
    xtp[(size_t)(p0 + ty + i) * C_ + c0 + tx] = f2bf(tile[tx][ty + i]);
}

// ---------------- Kernel 2: w_deform (O,C,3,3) -> bf16 Wp[o][k*256+c]
__global__ __launch_bounds__(256) void k_wt(const float* __restrict__ w,
                                            unsigned short* __restrict__ wp) {
  int idx = blockIdx.x * 256 + threadIdx.x;
  if (idx >= O_ * GK) return;
  int o = idx / GK;
  int kk = idx - o * GK;
  int k = kk >> 8;
  int c = kk & 255;
  wp[idx] = f2bf(w[(size_t)(o * C_ + c) * 9 + k]);
}

// ---------------- Kernel 3: offset convs (tm:4, tr:2) -> absolute sample coords
#define WSEC 386  // 64*6 + 2 pad words
__global__ __launch_bounds__(256) void k_offsets(const float* __restrict__ x,
                                                 const float* __restrict__ w_tm,
                                                 const float* __restrict__ b_tm,
                                                 const float* __restrict__ w_tr,
                                                 const float* __restrict__ b_tr,
                                                 float* __restrict__ coords) {
  __shared__ float lw[36 * WSEC];  // 55,584 B
  const int tid = threadIdx.x;
  for (int idx = tid; idx < 9 * 256 * 6; idx += 256) {
    int k = idx / 1536;
    int rem = idx - k * 1536;
    int c = rem / 6;
    int j = rem - c * 6;
    float v = (j < 4) ? w_tm[(size_t)(j * C_ + c) * 9 + k]
                      : w_tr[(size_t)((j - 4) * C_ + c) * 9 + k];
    lw[(k * 4 + (c >> 6)) * WSEC + (c & 63) * 6 + j] = v;
  }
  __syncthreads();

  const int wave = tid >> 6, lane = tid & 63;
  const int mm = lane & 15, q = lane >> 4;
  const int m = blockIdx.x * 64 + wave * 16 + mm;
  const int n = m / HW_;
  const int hw = m - n * HW_;
  const int h = hw / W_;
  const int w = hw - h * W_;
  const float* xb = x + (size_t)n * C_ * HW_ + (size_t)(q * 64) * HW_ + hw;

  float a0 = 0.f, a1 = 0.f, a2 = 0.f, a3 = 0.f, a4 = 0.f, a5 = 0.f;
#pragma unroll
  for (int ky = 0; ky < 3; ky++) {
    const int y = h + ky - 1;
    const bool vy = (y >= 0) && (y < H_);
#pragma unroll
    for (int kx = 0; kx < 3; kx++) {
      const int xx = w + kx - 1;
      const bool valid = vy && (xx >= 0) && (xx < W_);
      const float* xp = xb + (ky - 1) * W_ + (kx - 1);
      const float* wk = lw + ((ky * 3 + kx) * 4 + q) * WSEC;
#pragma unroll 8
      for (int cc = 0; cc < 64; cc++) {
        float xv = valid ? xp[(size_t)cc * HW_] : 0.f;
        const float* wr = wk + cc * 6;
        a0 += xv * wr[0];
        a1 += xv * wr[1];
        a2 += xv * wr[2];
        a3 += xv * wr[3];
        a4 += xv * wr[4];
        a5 += xv * wr[5];
      }
    }
  }
  a0 += __shfl_xor(a0, 16, 64); a0 += __shfl_xor(a0, 32, 64);
  a1 += __shfl_xor(a1, 16, 64); a1 += __shfl_xor(a1, 32, 64);
  a2 += __shfl_xor(a2, 16, 64); a2 += __shfl_xor(a2, 32, 64);
  a3 += __shfl_xor(a3, 16, 64); a3 += __shfl_xor(a3, 32, 64);
  a4 += __shfl_xor(a4, 16, 64); a4 += __shfl_xor(a4, 32, 64);
  a5 += __shfl_xor(a5, 16, 64); a5 += __shfl_xor(a5, 32, 64);

  if (q == 0) {
    const float tm0 = a0 + b_tm[0];
    const float tm1 = a1 + b_tm[1];
    const float tm2 = a2 + b_tm[2];
    const float tm3 = a3 + b_tm[3];
    const float tr0 = a4 + b_tr[0];
    const float tr1 = a5 + b_tr[1];
#pragma unroll
    for (int t = 0; t < 9; t++) {
      const float ry = (float)(t / 3) - 1.f;
      const float rx = (float)(t % 3) - 1.f;
      coords[(size_t)m * 18 + t * 2 + 0] = (float)h + tr0 + tm0 * ry + tm1 * rx;
      coords[(size_t)m * 18 + t * 2 + 1] = (float)w + tr1 + tm2 * ry + tm3 * rx;
    }
  }
}

// ---------------- Kernel 4: bilinear sampling (bf16 xt) -> bf16 A[m][k*256+c]
// Lane handles 4 consecutive channels: ushort4 loads per corner, ushort4 store.
__global__ __launch_bounds__(256) void k_sample(const unsigned short* __restrict__ xt,
                                                const float* __restrict__ coords,
                                                unsigned short* __restrict__ A) {
  const int wave = threadIdx.x >> 6, lane = threadIdx.x & 63;
  const int p = blockIdx.x * 4 + wave;  // (m,k) pair, < 165888
  const int m = p / 9;
  const int k = p - m * 9;
  const int n = m / HW_;
  const float py = coords[(size_t)m * 18 + k * 2 + 0];
  const float px = coords[(size_t)m * 18 + k * 2 + 1];
  const float fy = floorf(py), fx = floorf(px);
  const float wy = py - fy, wx = px - fx;
  const int y0 = (int)fy, x0 = (int)fx;
  const int y1 = y0 + 1, x1 = x0 + 1;
  const float vy0 = (y0 >= 0 && y0 < H_) ? 1.f : 0.f;
  const float vy1 = (y1 >= 0 && y1 < H_) ? 1.f : 0.f;
  const float vx0 = (x0 >= 0 && x0 < W_) ? 1.f : 0.f;
  const float vx1 = (x1 >= 0 && x1 < W_) ? 1.f : 0.f;
  const float w00 = (1.f - wy) * (1.f - wx) * vy0 * vx0;
  const float w01 = (1.f - wy) * wx * vy0 * vx1;
  const float w10 = wy * (1.f - wx) * vy1 * vx0;
  const float w11 = wy * wx * vy1 * vx1;
  const int cy0 = min(max(y0, 0), H_ - 1), cy1 = min(max(y1, 0), H_ - 1);
  const int cx0 = min(max(x0, 0), W_ - 1), cx1 = min(max(x1, 0), W_ - 1);
  const us4* r00 = (const us4*)(xt + (size_t)((n * H_ + cy0) * W_ + cx0) * C_) + lane;
  const us4* r01 = (const us4*)(xt + (size_t)((n * H_ + cy0) * W_ + cx1) * C_) + lane;
  const us4* r10 = (const us4*)(xt + (size_t)((n * H_ + cy1) * W_ + cx0) * C_) + lane;
  const us4* r11 = (const us4*)(xt + (size_t)((n * H_ + cy1) * W_ + cx1) * C_) + lane;
  const us4 u00 = *r00, u01 = *r01, u10 = *r10, u11 = *r11;
  us4 res;
#pragma unroll
  for (int i = 0; i < 4; i++) {
    float v = w00 * bf2f(u00[i]) + w01 * bf2f(u01[i]) +
              w10 * bf2f(u10[i]) + w11 * bf2f(u11[i]);
    res[i] = f2bf(v);
  }
  ((us4*)(A + (size_t)m * GK + k * C_))[lane] = res;
}

// ---------------- Kernel 5: GEMM out[m][o] = sum_kk A[m][kk]*Wp[o][kk], fused BN+res+ReLU
// 64x128 tile -> 576 blocks (2.25/CU). BK=64. XOR chunk swizzle (global-side
// address permute: LDS slot j of row r holds global chunk j^(r&7)) spreads the
// 16 rows of each ds_read_b128 over all 32 banks (row stride 128 B = 32 banks
// would otherwise alias every row to bank 0 -> the 7.96M conflict cycles seen).
__global__ __launch_bounds__(256, 4) void k_gemm(const unsigned short* __restrict__ A,
                                                 const unsigned short* __restrict__ Wp,
                                                 const float* __restrict__ xres,
                                                 const float* __restrict__ gamma,
                                                 const float* __restrict__ beta,
                                                 const float* __restrict__ mean,
                                                 const float* __restrict__ var,
                                                 float* __restrict__ out) {
  __shared__ unsigned short As[64 * 64] __attribute__((aligned(16)));
  __shared__ unsigned short Bs[128 * 64] __attribute__((aligned(16)));
  const int tid = threadIdx.x;
  const int wave = tid >> 6, lane = tid & 63;
  const int wm = wave & 1, wo = wave >> 1;      // m-half (32), o-half (64)
  const int bo = blockIdx.x & 1, bm = blockIdx.x >> 1;
  const int m0 = bm * 64, o0 = bo * 128;
  const int row = lane & 15, quad = lane >> 4;

  f32x4 acc[2][4] = {};

  for (int k0 = 0; k0 < GK; k0 += 64) {
#pragma unroll
    for (int i = 0; i < 2; i++) {           // As: 512 chunks of 16B
      int g = i * 256 + tid;
      int r = g >> 3, j = g & 7;
      int gc = j ^ (r & 7);
      __builtin_amdgcn_global_load_lds(
          (const __attribute__((address_space(1))) void*)(A + (size_t)(m0 + r) * GK + k0 + gc * 8),
          (__attribute__((address_space(3))) void*)(&As[(size_t)g * 8]),
          16, 0, 0);
    }
#pragma unroll
    for (int i = 0; i < 4; i++) {           // Bs: 1024 chunks of 16B
      int g = i * 256 + tid;
      int r = g >> 3, j = g & 7;
      int gc = j ^ (r & 7);
      __builtin_amdgcn_global_load_lds(
          (const __attribute__((address_space(1))) void*)(Wp + (size_t)(o0 + r) * GK + k0 + gc * 8),
          (__attribute__((address_space(3))) void*)(&Bs[(size_t)g * 8]),
          16, 0, 0);
    }
    __syncthreads();
#pragma unroll
    for (int ks = 0; ks < 64; ks += 32) {
      const int cb = ks >> 3;  // chunk base: 0 or 4
      bf16x8 av[2], bv[4];
#pragma unroll
      for (int mt = 0; mt < 2; mt++) {
        int r = wm * 32 + mt * 16 + row;
        av[mt] = *(const bf16x8*)(const void*)&As[r * 64 + (((cb + quad) ^ (r & 7)) << 3)];
      }
#pragma unroll
      for (int ot = 0; ot < 4; ot++) {
        int r = wo * 64 + ot * 16 + row;
        bv[ot] = *(const bf16x8*)(const void*)&Bs[r * 64 + (((cb + quad) ^ (r & 7)) << 3)];
      }
#pragma unroll
      for (int mt = 0; mt < 2; mt++)
#pragma unroll
        for (int ot = 0; ot < 4; ot++)
          acc[mt][ot] = __builtin_amdgcn_mfma_f32_16x16x32_bf16(av[mt], bv[ot], acc[mt][ot], 0, 0, 0);
    }
    __syncthreads();
  }

  const int n = m0 / HW_;  // 64 | 9216, tiles never cross n
#pragma unroll
  for (int ot = 0; ot < 4; ot++) {
    int o = o0 + wo * 64 + ot * 16 + row;
    float sc = rsqrtf(var[o] + 1e-5f) * gamma[o];
    float bi = beta[o] - mean[o] * sc;
    const size_t obase = (size_t)(n * O_ + o) * HW_;
#pragma unroll
    for (int mt = 0; mt < 2; mt++) {
      int mrow = m0 + wm * 32 + mt * 16 + quad * 4 - n * HW_;
#pragma unroll
      for (int r = 0; r < 4; r++) {
        int hw = mrow + r;
        float v = acc[mt][ot][r] * sc + bi + xres[obase + hw];
        out[obase + hw] = fmaxf(v, 0.f);
      }
    }
  }
}

extern "C" void kernel_launch(void* const* d_in, const int* in_sizes, int n_in,
                              void* d_out, int out_size, void* d_ws, size_t ws_size,
                              hipStream_t stream) {
  const float* x     = (const float*)d_in[0];
  const float* w_tm  = (const float*)d_in[2];
  const float* b_tm  = (const float*)d_in[3];
  const float* w_tr  = (const float*)d_in[4];
  const float* b_tr  = (const float*)d_in[5];
  const float* w_df  = (const float*)d_in[6];
  const float* gamma = (const float*)d_in[7];
  const float* beta  = (const float*)d_in[8];
  const float* mean  = (const float*)d_in[9];
  const float* var   = (const float*)d_in[10];
  float* out = (float*)d_out;

  char* ws = (char*)d_ws;
  unsigned short* xt   = (unsigned short*)(ws);                            //  9,437,184 B
  float* coords        = (float*)(ws + 9437184);                           //  1,327,104 B
  unsigned short* WpB  = (unsigned short*)(ws + 9437184 + 1327104);        //  1,179,648 B
  unsigned short* Amat = (unsigned short*)(ws + 9437184 + 1327104 + 1179648); // 84,934,656 B

  k_transpose<<<dim3(HW_ / 32, C_ / 32, N_), dim3(32, 8), 0, stream>>>(x, xt);
  k_wt<<<(O_ * GK) / 256, 256, 0, stream>>>(w_df, WpB);
  k_offsets<<<M_ / 64, 256, 0, stream>>>(x, w_tm, b_tm, w_tr, b_tr, coords);
  k_sample<<<(M_ * 9) / 4, 256, 0, stream>>>(xt, coords, Amat);
  k_gemm<<<(M_ / 64) * 2, 256, 0, stream>>>(Amat, WpB, x, gamma, beta, mean, var, out);
}